// Round 15
// baseline (291.796 us; speedup 1.0000x reference)
//
#include <hip/hip_runtime.h>

#define N_S   65536
#define DXF   1024
#define DD    256
#define NM1   65535.0f
#define EPSR  0.001f

typedef __attribute__((ext_vector_type(4)))  float          f32x4;
typedef __attribute__((ext_vector_type(16))) float          f32x16;
typedef __attribute__((ext_vector_type(8)))  short          bf16x8;
typedef __attribute__((ext_vector_type(4)))  unsigned short ushort4_t;
typedef __attribute__((ext_vector_type(8)))  unsigned short ushort8_t;

__device__ __forceinline__ unsigned short f2bf(float f){
  unsigned u = __float_as_uint(f);
  u += 0x7fffu + ((u >> 16) & 1u);   // RNE
  return (unsigned short)(u >> 16);
}
__device__ __forceinline__ float bf2f(unsigned short h){
  return __uint_as_float(((unsigned)h) << 16);
}
__device__ __forceinline__ f32x4 mfma16(bf16x8 a, bf16x8 b, f32x4 c){
  return __builtin_amdgcn_mfma_f32_16x16x32_bf16(a, b, c, 0, 0, 0);
}
__device__ __forceinline__ f32x16 mfma32(bf16x8 a, bf16x8 b, f32x16 c){
  return __builtin_amdgcn_mfma_f32_32x32x16_bf16(a, b, c, 0, 0, 0);
}
__device__ __forceinline__ void gld_lds16(const void* g, void* l){
  __builtin_amdgcn_global_load_lds(
      (const __attribute__((address_space(1))) unsigned int*)g,
      (__attribute__((address_space(3))) unsigned int*)l, 16, 0, 0);
}

#define VMCNT(N) asm volatile("s_waitcnt vmcnt(" #N ")" ::: "memory")

// ------- W' in k-chunk-major bf16 layout + STG regularizer accumulation ----
__global__ void k_prep(const float* __restrict__ Wx, const float* __restrict__ Wy,
                       const float* __restrict__ mux, const float* __restrict__ muy,
                       unsigned short* __restrict__ WTx, unsigned short* __restrict__ WTy,
                       float* __restrict__ scal){
  int v = blockIdx.y;
  const float* W  = v ? Wy  : Wx;
  const float* mu = v ? muy : mux;
  unsigned short* WT = v ? WTy : WTx;
  int j = threadIdx.x;
  if (j < 4){
    float ph = 0.5f * (1.f + erff(mu[blockIdx.x * 4 + j] * 1.41421356237f));
    atomicAdd(scal + 2 + v, 9.765625e-5f * ph);
  }
  #pragma unroll
  for (int r = 0; r < 4; ++r){
    int k = blockIdx.x * 4 + r;
    float g = fminf(fmaxf(mu[k] + 0.5f, 0.f), 1.f);
    WT[(size_t)(k >> 3) * 2048 + j * 8 + (k & 7)] = f2bf(g * W[(size_t)k * DD + j]);
  }
}

// ---------------- big GEMM: Xh = X @ W'  -> bf16 ---------------------------
// R13 + K-chunk 256: each A-row visited once per chunk with 1KB contiguous
// (1KB DRAM bursts, 2x R13). Single 32KB As buffer, 32-slot XOR swizzle
// (slot^row&15: reads/writes at 8-round bank minimum). B in two 8-frag
// halves per chunk; counted vmcnt {14..8}; 3 drains / 8 barriers total.
__global__ __launch_bounds__(512, 4) void k_gemm13(
    const float* __restrict__ X, const float* __restrict__ Y,
    const unsigned short* __restrict__ WTx, const unsigned short* __restrict__ WTy,
    unsigned short* __restrict__ Xhb, unsigned short* __restrict__ Yhb){
  const float* A = blockIdx.z ? Y : X;
  const unsigned short* WT = blockIdx.z ? WTy : WTx;
  unsigned short* Out = blockIdx.z ? Yhb : Xhb;

  __shared__ unsigned short As[64][256];       // 32KB single buffer, swizzled

  int tid = threadIdx.x, lane = tid & 63, wid = tid >> 6;
  int row0 = blockIdx.x * 64;

  f32x4 acc[4][2] = {};

  int s_row = tid >> 3, s_p = tid & 7;         // 64 rows x 8 base slots
  const float* ap = A + (size_t)(row0 + s_row) * DXF + s_p * 8;

  // B fragment base: col = wid*32 + t*16 + (lane&15); k-group = (lane>>4)
  const unsigned short* bB = WT + (size_t)(lane >> 4) * 2048
                           + (wid * 32 + (lane & 15)) * 8;

  float4 a0, a1, a2, a3, a4, a5, a6, a7;
  auto loadA = [&](int kc){                    // 8 float4 = 1KB/row over 8 thr
    const float* p = ap + kc * 256;
    a0 = *(const float4*)(p);        a1 = *(const float4*)(p + 4);
    a2 = *(const float4*)(p + 64);   a3 = *(const float4*)(p + 68);
    a4 = *(const float4*)(p + 128);  a5 = *(const float4*)(p + 132);
    a6 = *(const float4*)(p + 192);  a7 = *(const float4*)(p + 196);
  };
  auto cvt2 = [](float4 x, float4 y) -> ushort8_t {
    union { unsigned u[4]; ushort8_t v; } w;
    asm("v_cvt_pk_bf16_f32 %0, %1, %2" : "=v"(w.u[0]) : "v"(x.x), "v"(x.y));
    asm("v_cvt_pk_bf16_f32 %0, %1, %2" : "=v"(w.u[1]) : "v"(x.z), "v"(x.w));
    asm("v_cvt_pk_bf16_f32 %0, %1, %2" : "=v"(w.u[2]) : "v"(y.x), "v"(y.y));
    asm("v_cvt_pk_bf16_f32 %0, %1, %2" : "=v"(w.u[3]) : "v"(y.z), "v"(y.w));
    return w.v;
  };
  auto writeA = [&](){
    int r15 = s_row & 15;
    *(ushort8_t*)&As[s_row][((s_p     ) ^ r15) * 8] = cvt2(a0, a1);
    *(ushort8_t*)&As[s_row][((s_p +  8) ^ r15) * 8] = cvt2(a2, a3);
    *(ushort8_t*)&As[s_row][((s_p + 16) ^ r15) * 8] = cvt2(a4, a5);
    *(ushort8_t*)&As[s_row][((s_p + 24) ^ r15) * 8] = cvt2(a6, a7);
  };

  // prologue: chunk 0 staged synchronously
  loadA(0);
  VMCNT(0);
  writeA();
  asm volatile("s_waitcnt lgkmcnt(0)" ::: "memory");
  __builtin_amdgcn_s_barrier();

#define AFRAG(M, S) \
    (*(const bf16x8*)&As[M * 16 + (lane & 15)] \
        [(((S * 4) + (lane >> 4)) ^ (lane & 15)) * 8])
#define GSTEP(S, BA, BB) { \
    bf16x8 af0 = AFRAG(0, S); \
    bf16x8 af1 = AFRAG(1, S); \
    bf16x8 af2 = AFRAG(2, S); \
    bf16x8 af3 = AFRAG(3, S); \
    acc[0][0] = mfma16(af0, BA, acc[0][0]); acc[0][1] = mfma16(af0, BB, acc[0][1]); \
    acc[1][0] = mfma16(af1, BA, acc[1][0]); acc[1][1] = mfma16(af1, BB, acc[1][1]); \
    acc[2][0] = mfma16(af2, BA, acc[2][0]); acc[2][1] = mfma16(af2, BB, acc[2][1]); \
    acc[3][0] = mfma16(af3, BA, acc[3][0]); acc[3][1] = mfma16(af3, BB, acc[3][1]); }

  #pragma unroll
  for (int c = 0; c < 4; ++c){
    const unsigned short* bc = bB + (size_t)c * 65536;
    // B half 0 (GSTEPs 0-3), then A(c+1): B older in queue
    bf16x8 b0a = *(const bf16x8*)(bc);
    bf16x8 b0b = *(const bf16x8*)(bc + 128);
    bf16x8 b1a = *(const bf16x8*)(bc + 8192);
    bf16x8 b1b = *(const bf16x8*)(bc + 8320);
    bf16x8 b2a = *(const bf16x8*)(bc + 16384);
    bf16x8 b2b = *(const bf16x8*)(bc + 16512);
    bf16x8 b3a = *(const bf16x8*)(bc + 24576);
    bf16x8 b3b = *(const bf16x8*)(bc + 24704);
    asm volatile("" ::: "memory");
    if (c < 3) loadA(c + 1);                   // 8 loads, newest

    if (c < 3) { VMCNT(14); } else { VMCNT(6); }
    __builtin_amdgcn_sched_barrier(0);
    GSTEP(0, b0a, b0b)
    if (c < 3) { VMCNT(12); } else { VMCNT(4); }
    __builtin_amdgcn_sched_barrier(0);
    GSTEP(1, b1a, b1b)
    if (c < 3) { VMCNT(10); } else { VMCNT(2); }
    __builtin_amdgcn_sched_barrier(0);
    GSTEP(2, b2a, b2b)
    if (c < 3) { VMCNT(8); } else { VMCNT(0); }
    __builtin_amdgcn_sched_barrier(0);
    GSTEP(3, b3a, b3b)

    // B half 1 (GSTEPs 4-7): queue = A(8 older) + B1(8)
    bf16x8 b4a = *(const bf16x8*)(bc + 32768);
    bf16x8 b4b = *(const bf16x8*)(bc + 32896);
    bf16x8 b5a = *(const bf16x8*)(bc + 40960);
    bf16x8 b5b = *(const bf16x8*)(bc + 41088);
    bf16x8 b6a = *(const bf16x8*)(bc + 49152);
    bf16x8 b6b = *(const bf16x8*)(bc + 49280);
    bf16x8 b7a = *(const bf16x8*)(bc + 57344);
    bf16x8 b7b = *(const bf16x8*)(bc + 57472);
    asm volatile("" ::: "memory");

    if (c < 3) { VMCNT(14); } else { VMCNT(6); }
    __builtin_amdgcn_sched_barrier(0);
    GSTEP(4, b4a, b4b)
    if (c < 3) { VMCNT(12); } else { VMCNT(4); }
    __builtin_amdgcn_sched_barrier(0);
    GSTEP(5, b5a, b5b)
    if (c < 3) { VMCNT(10); } else { VMCNT(2); }
    __builtin_amdgcn_sched_barrier(0);
    GSTEP(6, b6a, b6b)
    if (c < 3) { VMCNT(8); } else { VMCNT(0); }
    __builtin_amdgcn_sched_barrier(0);
    GSTEP(7, b7a, b7b)

    if (c < 3){
      __builtin_amdgcn_s_barrier();            // all waves done reading As
      VMCNT(0);                                // A(c+1) regs ready
      __builtin_amdgcn_sched_barrier(0);
      writeA();
      asm volatile("s_waitcnt lgkmcnt(0)" ::: "memory");
      __builtin_amdgcn_s_barrier();
    }
  }
#undef GSTEP
#undef AFRAG

  // epilogue: LDS transpose (flat 32KB in As) -> coalesced bf16 stores
  __syncthreads();
  unsigned short* tl = &As[0][0];
  #pragma unroll
  for (int r = 0; r < 4; ++r)
    #pragma unroll
    for (int t = 0; t < 2; ++t)
      #pragma unroll
      for (int rr = 0; rr < 4; ++rr){
        int row = r * 16 + (lane >> 4) * 4 + rr;
        int col = wid * 32 + t * 16 + (lane & 15);
        tl[row * 256 + col] = f2bf(acc[r][t][rr]);
      }
  __syncthreads();
  unsigned short* ob = Out + (size_t)row0 * DD;
  #pragma unroll
  for (int r = 0; r < 4; ++r){
    int off = r * 4096 + tid * 8;
    *(ushort8_t*)(ob + off) = *(const ushort8_t*)(tl + off);
  }
}

// ---------------- Gram kernel: split-K partials (unchanged) ----------------
__global__ __launch_bounds__(512) void k_gram(
    const unsigned short* __restrict__ Xhb, const unsigned short* __restrict__ Yhb,
    float* __restrict__ part, float* __restrict__ sx, float* __restrict__ sy, int P){
  int type = blockIdx.z;
  int p = blockIdx.x;
  int chunk = N_S / P;
  int r0 = p * chunk;
  const unsigned short* Asrc = (type == 0) ? Xhb : Yhb;
  const unsigned short* Bsrc = (type == 1) ? Yhb : Xhb;
  bool dualB = (type == 2);

  __shared__ unsigned short At[256][40];
  __shared__ unsigned short Bt[256][40];

  int tid = threadIdx.x;
  int lane = tid & 63, wid = tid >> 6;
  int wr = wid >> 1, wc = wid & 1;

  f32x4 acc[4][8] = {};
  float cs0 = 0.f, cs1 = 0.f;

  int cp  = tid & 127;
  int kb0 = tid >> 7;

  unsigned ua[2][4], ub[2][4];

  auto loadT = [&](int ks){
    int base = r0 + ks * 32;
    #pragma unroll
    for (int r = 0; r < 2; ++r){
      int kb = kb0 + r * 4;
      #pragma unroll
      for (int kr = 0; kr < 4; ++kr){
        ua[r][kr] = *(const unsigned*)(Asrc + (size_t)(base + kb * 4 + kr) * DD + cp * 2);
        if (dualB)
          ub[r][kr] = *(const unsigned*)(Bsrc + (size_t)(base + kb * 4 + kr) * DD + cp * 2);
      }
    }
  };
  auto storeT = [&](){
    #pragma unroll
    for (int r = 0; r < 2; ++r){
      int kb = kb0 + r * 4;
      ushort4_t lo = { (unsigned short)ua[r][0], (unsigned short)ua[r][1],
                       (unsigned short)ua[r][2], (unsigned short)ua[r][3] };
      ushort4_t hi = { (unsigned short)(ua[r][0] >> 16), (unsigned short)(ua[r][1] >> 16),
                       (unsigned short)(ua[r][2] >> 16), (unsigned short)(ua[r][3] >> 16) };
      *(ushort4_t*)&At[cp * 2][kb * 4]     = lo;
      *(ushort4_t*)&At[cp * 2 + 1][kb * 4] = hi;
      if (type < 2){
        #pragma unroll
        for (int kr = 0; kr < 4; ++kr){
          cs0 += bf2f((unsigned short)ua[r][kr]);
          cs1 += bf2f((unsigned short)(ua[r][kr] >> 16));
        }
      }
      if (dualB){
        ushort4_t lob = { (unsigned short)ub[r][0], (unsigned short)ub[r][1],
                          (unsigned short)ub[r][2], (unsigned short)ub[r][3] };
        ushort4_t hib = { (unsigned short)(ub[r][0] >> 16), (unsigned short)(ub[r][1] >> 16),
                          (unsigned short)(ub[r][2] >> 16), (unsigned short)(ub[r][3] >> 16) };
        *(ushort4_t*)&Bt[cp * 2][kb * 4]     = lob;
        *(ushort4_t*)&Bt[cp * 2 + 1][kb * 4] = hib;
      }
    }
  };

  unsigned short (*Btp)[40] = dualB ? Bt : At;

  int KS = chunk / 32;
  loadT(0);
  for (int ks = 0; ks < KS; ++ks){
    __syncthreads();
    storeT();
    __syncthreads();
    if (ks + 1 < KS) loadT(ks + 1);
    bf16x8 af[4], bfv[8];
    #pragma unroll
    for (int mi = 0; mi < 4; ++mi)
      af[mi] = *(const bf16x8*)&At[wr * 64 + mi * 16 + (lane & 15)][(lane >> 4) * 8];
    #pragma unroll
    for (int ni = 0; ni < 8; ++ni)
      bfv[ni] = *(const bf16x8*)&Btp[wc * 128 + ni * 16 + (lane & 15)][(lane >> 4) * 8];
    #pragma unroll
    for (int mi = 0; mi < 4; ++mi)
      #pragma unroll
      for (int ni = 0; ni < 8; ++ni)
        acc[mi][ni] = mfma16(af[mi], bfv[ni], acc[mi][ni]);
  }

  float* dst = part + ((size_t)p * 3 + type) * 65536;
  #pragma unroll
  for (int mi = 0; mi < 4; ++mi)
    #pragma unroll
    for (int ni = 0; ni < 8; ++ni)
      #pragma unroll
      for (int rr = 0; rr < 4; ++rr){
        int grow = wr * 64 + mi * 16 + (lane >> 4) * 4 + rr;
        int gcol = wc * 128 + ni * 16 + (lane & 15);
        dst[(size_t)grow * 256 + gcol] = acc[mi][ni][rr];
      }

  if (type < 2){
    __syncthreads();
    float* red = (float*)&At[0][0];
    red[kb0 * 256 + cp * 2]     = cs0;
    red[kb0 * 256 + cp * 2 + 1] = cs1;
    __syncthreads();
    if (tid < 256){
      float s = red[tid] + red[256 + tid] + red[512 + tid] + red[768 + tid];
      atomicAdd((type == 0 ? sx : sy) + tid, s);
    }
  }
}

// -------- reduce partials -> A,B (fp32+bf16), C bf16(+T), inf-norms --------
__global__ void k_reduce(const float* __restrict__ part, const float* __restrict__ sx,
                         const float* __restrict__ sy, float* __restrict__ Am,
                         float* __restrict__ Bm,
                         unsigned short* __restrict__ Abf, unsigned short* __restrict__ Bbf,
                         unsigned short* __restrict__ Cbf, unsigned short* __restrict__ CbfT,
                         float* __restrict__ scal, int P){
  __shared__ float r2[256];
  int i = blockIdx.x, j = threadIdx.x;
  size_t idx = (size_t)i * 256 + j;
  float gxx = 0.f, gyy = 0.f, gyx = 0.f;
  for (int p = 0; p < P; ++p){
    const float* b = part + (size_t)p * 3 * 65536;
    gxx += b[idx];
    gyy += b[65536 + idx];
    gyx += b[131072 + idx];
  }
  float invn1 = 1.f / NM1;
  float invn  = 1.f / (float)N_S;
  float sxi = sx[i], sxj = sx[j], syi = sy[i], syj = sy[j];
  float diag = (i == j) ? 1.f : 0.f;
  float am = (gyy - syi * syj * invn) * invn1 + diag * (2.f * EPSR);
  float bm = (gxx - sxi * sxj * invn) * invn1 + diag * EPSR;
  float cv = (gyx - syi * sxj * invn) * invn1;
  Am[idx] = am;  Bm[idx] = bm;
  Abf[idx] = f2bf(am);
  Bbf[idx] = f2bf(bm);
  Cbf[idx] = f2bf(cv);
  CbfT[(size_t)j * 256 + i] = f2bf(cv);
  r2[j] = fabsf(am);
  __syncthreads();
  for (int s = 128; s > 0; s >>= 1){ if (j < s) r2[j] += r2[j + s]; __syncthreads(); }
  if (j == 0) atomicMax((unsigned*)scal + 5, __float_as_uint(r2[0]));
  __syncthreads();
  r2[j] = fabsf(bm);
  __syncthreads();
  for (int s = 128; s > 0; s >>= 1){ if (j < s) r2[j] += r2[j + s]; __syncthreads(); }
  if (j == 0) atomicMax((unsigned*)scal + 6, __float_as_uint(r2[0]));
}

// -------- X1 = 2aI - a^2 M  (NS step 1 closed form), a = 1.9/||M||inf ------
__global__ void k_x1(const float* __restrict__ Am, const float* __restrict__ Bm,
                     unsigned short* __restrict__ X0, const float* __restrict__ scal){
  int m = blockIdx.y;
  const unsigned* su = (const unsigned*)scal;
  float al = 1.9f / __uint_as_float(su[5 + m]);
  const float* M = m ? Bm : Am;
  int e = blockIdx.x * 512 + threadIdx.x;
  float v = -al * al * M[e];
  if ((e >> 8) == (e & 255)) v += 2.f * al;
  X0[m * 65536 + e] = f2bf(v);
}

// -------- one NS iteration, col-block local: X'_j = 2X_j - X*(M*X_j) -------
__global__ __launch_bounds__(512) void k_it(
    const unsigned short* __restrict__ Abf, const unsigned short* __restrict__ Bbf,
    const unsigned short* __restrict__ Xc, unsigned short* __restrict__ Xn){
  int m = blockIdx.y, j = blockIdx.x;
  const unsigned short* M  = m ? Bbf : Abf;
  const unsigned short* Xm = Xc + m * 65536;
  unsigned short*       Xo = Xn + m * 65536;

  __shared__ unsigned short XJ[32 * 256];
  __shared__ unsigned short TT[32 * 256];

  int tid = threadIdx.x, lane = tid & 63, w = tid >> 6;
  int r31 = lane & 31, kh = lane >> 5;

  #pragma unroll
  for (int i = 0; i < 2; ++i){
    int rl = w * 4 + i * 2 + kh;
    int cg = ((lane & 31) - rl) & 31;
    gld_lds16(Xm + (size_t)(j * 32 + rl) * 256 + cg * 8, &XJ[(w * 4 + i * 2) * 256]);
  }
  asm volatile("s_waitcnt vmcnt(0)" ::: "memory");
  __builtin_amdgcn_s_barrier();

  f32x16 acc = {};
  const unsigned short* arow = M + (size_t)(w * 32 + r31) * 256 + kh * 8;
  #pragma unroll
  for (int ks = 0; ks < 16; ++ks){
    bf16x8 af = *(const bf16x8*)(arow + ks * 16);
    int ch = ((ks * 2 + kh) + r31) & 31;
    bf16x8 bf = *(const bf16x8*)&XJ[r31 * 256 + ch * 8];
    acc = mfma32(af, bf, acc);
  }
  #pragma unroll
  for (int reg = 0; reg < 16; ++reg){
    int kk = w * 32 + (reg & 3) + ((reg >> 2) << 3) + (kh << 2);
    int ch = ((kk >> 3) + r31) & 31;
    TT[r31 * 256 + ch * 8 + (kk & 7)] = f2bf(acc[reg]);
  }
  __syncthreads();

  f32x16 acc2 = {};
  const unsigned short* xrow = Xm + (size_t)(w * 32 + r31) * 256 + kh * 8;
  #pragma unroll
  for (int ks = 0; ks < 16; ++ks){
    bf16x8 af = *(const bf16x8*)(xrow + ks * 16);
    int ch = ((ks * 2 + kh) + r31) & 31;
    bf16x8 bf = *(const bf16x8*)&TT[r31 * 256 + ch * 8];
    acc2 = mfma32(af, bf, acc2);
  }
  #pragma unroll
  for (int reg = 0; reg < 16; ++reg){
    int row = w * 32 + (reg & 3) + ((reg >> 2) << 3) + (kh << 2);
    int ch = ((row >> 3) + r31) & 31;
    float xv = bf2f(XJ[r31 * 256 + ch * 8 + (row & 7)]);
    Xo[(size_t)row * 256 + j * 32 + r31] = f2bf(2.f * xv - acc2[reg]);
  }
}

// -------- U = XA*C (mat0) ; W = C*XB = V^T (mat1) ; f32 outputs ------------
__global__ __launch_bounds__(512) void k_uv(
    const unsigned short* __restrict__ Xf,
    const unsigned short* __restrict__ Cbf, const unsigned short* __restrict__ CbfT,
    float* __restrict__ U, float* __restrict__ W){
  int m = blockIdx.y, j = blockIdx.x;
  __shared__ unsigned short BJ[32 * 256];
  int tid = threadIdx.x, lane = tid & 63, w = tid >> 6;
  int r31 = lane & 31, kh = lane >> 5;
  const unsigned short* Brows = m ? (Xf + 65536) : CbfT;
  const unsigned short* Arows = m ? Cbf : Xf;
  float* D = m ? W : U;

  #pragma unroll
  for (int i = 0; i < 2; ++i){
    int rl = w * 4 + i * 2 + kh;
    int cg = ((lane & 31) - rl) & 31;
    gld_lds16(Brows + (size_t)(j * 32 + rl) * 256 + cg * 8, &BJ[(w * 4 + i * 2) * 256]);
  }
  asm volatile("s_waitcnt vmcnt(0)" ::: "memory");
  __builtin_amdgcn_s_barrier();

  f32x16 acc = {};
  const unsigned short* ar = Arows + (size_t)(w * 32 + r31) * 256 + kh * 8;
  #pragma unroll
  for (int ks = 0; ks < 16; ++ks){
    bf16x8 af = *(const bf16x8*)(ar + ks * 16);
    int ch = ((ks * 2 + kh) + r31) & 31;
    bf16x8 bf = *(const bf16x8*)&BJ[r31 * 256 + ch * 8];
    acc = mfma32(af, bf, acc);
  }
  #pragma unroll
  for (int reg = 0; reg < 16; ++reg){
    int row = w * 32 + (reg & 3) + ((reg >> 2) << 3) + (kh << 2);
    D[(size_t)row * 256 + j * 32 + r31] = acc[reg];
  }
}

// -------- final: loss = -sum(U*W)/256 + regx + regy ------------------------
__global__ __launch_bounds__(1024) void k_fin(const float* __restrict__ U,
                                              const float* __restrict__ W,
                                              const float* __restrict__ scal,
                                              float* __restrict__ out){
  __shared__ float red[1024];
  int tid = threadIdx.x;
  float t = 0.f;
  #pragma unroll
  for (int r = 0; r < 16; ++r){
    int i = r * 4096 + tid * 4;
    float4 u = *(const float4*)(U + i);
    float4 w = *(const float4*)(W + i);
    t += u.x * w.x + u.y * w.y + u.z * w.z + u.w * w.w;
  }
  red[tid] = t; __syncthreads();
  for (int s = 512; s > 0; s >>= 1){ if (tid < s) red[tid] += red[tid + s]; __syncthreads(); }
  if (tid == 0) out[0] = -red[0] / 256.f + scal[2] + scal[3];
}

extern "C" void kernel_launch(void* const* d_in, const int* in_sizes, int n_in,
                              void* d_out, int out_size, void* d_ws, size_t ws_size,
                              hipStream_t stream){
  (void)in_sizes; (void)n_in; (void)out_size;
  const float* X   = (const float*)d_in[0];
  const float* Y   = (const float*)d_in[1];
  const float* mux = (const float*)d_in[2];
  const float* muy = (const float*)d_in[3];
  const float* Wx  = (const float*)d_in[4];
  const float* Wy  = (const float*)d_in[6];
  float* out = (float*)d_out;
  char* ws = (char*)d_ws;

  const size_t MB = 1ull << 20;
  const size_t KB = 1024;
  size_t oXHB = 0;
  size_t oYHB = 32 * MB;
  size_t oWTX = 64 * MB;
  size_t oWTY = oWTX + 512 * KB;
  size_t oSX  = oWTY + 512 * KB;
  size_t oSY  = oSX + 4 * KB;
  size_t oSC  = oSY + 4 * KB;
  size_t oA   = oSC + 4 * KB;
  size_t oB   = oA   + 256 * KB;
  size_t oABF = oB   + 256 * KB;
  size_t oBBF = oABF + 128 * KB;
  size_t oCBF = oBBF + 128 * KB;
  size_t oCBT = oCBF + 128 * KB;
  size_t oX0  = oCBT + 128 * KB;
  size_t oX1  = oX0  + 256 * KB;
  size_t oTB  = oX1  + 256 * KB;
  size_t oU   = oTB  + 256 * KB;
  size_t oV   = oU   + 256 * KB;
  size_t oPart = 68 * MB;

  size_t per = 3ull * 65536 * 4;
  int P = 64;
  while (P > 8 && oPart + (size_t)P * per > ws_size) P >>= 1;

  unsigned short* Xhb = (unsigned short*)(ws + oXHB);
  unsigned short* Yhb = (unsigned short*)(ws + oYHB);
  unsigned short* WTx = (unsigned short*)(ws + oWTX);
  unsigned short* WTy = (unsigned short*)(ws + oWTY);
  float* sx   = (float*)(ws + oSX);
  float* sy   = (float*)(ws + oSY);
  float* scal = (float*)(ws + oSC);
  float* Am   = (float*)(ws + oA);
  float* Bm   = (float*)(ws + oB);
  unsigned short* Abf  = (unsigned short*)(ws + oABF);
  unsigned short* Bbf  = (unsigned short*)(ws + oBBF);
  unsigned short* Cbf  = (unsigned short*)(ws + oCBF);
  unsigned short* CbfT = (unsigned short*)(ws + oCBT);
  unsigned short* X0   = (unsigned short*)(ws + oX0);
  unsigned short* X1   = (unsigned short*)(ws + oX1);
  float* U    = (float*)(ws + oU);
  float* V    = (float*)(ws + oV);
  float* part = (float*)(ws + oPart);

  hipMemsetAsync(ws + oSX, 0, 12 * KB, stream);

  k_prep<<<dim3(256, 2), 256, 0, stream>>>(Wx, Wy, mux, muy, WTx, WTy, scal);
  k_gemm13<<<dim3(1024, 1, 2), 512, 0, stream>>>(X, Y, WTx, WTy, Xhb, Yhb);
  k_gram<<<dim3(P, 1, 3), 512, 0, stream>>>(Xhb, Yhb, part, sx, sy, P);
  k_reduce<<<256, 256, 0, stream>>>(part, sx, sy, Am, Bm, Abf, Bbf, Cbf, CbfT, scal, P);

  k_x1<<<dim3(128, 2), 512, 0, stream>>>(Am, Bm, X0, scal);
  k_it<<<dim3(8, 2), 512, 0, stream>>>(Abf, Bbf, X0, X1);
  k_it<<<dim3(8, 2), 512, 0, stream>>>(Abf, Bbf, X1, X0);
  k_it<<<dim3(8, 2), 512, 0, stream>>>(Abf, Bbf, X0, X1);
  k_it<<<dim3(8, 2), 512, 0, stream>>>(Abf, Bbf, X1, X0);
  k_it<<<dim3(8, 2), 512, 0, stream>>>(Abf, Bbf, X0, X1);   // final in X1
  k_uv<<<dim3(8, 2), 512, 0, stream>>>(X1, Cbf, CbfT, U, V);
  k_fin<<<1, 1024, 0, stream>>>(U, V, scal, out);
}

// Round 16
// 286.055 us; speedup vs baseline: 1.0201x; 1.0201x over previous
//
#include <hip/hip_runtime.h>

#define N_S   65536
#define DXF   1024
#define DD    256
#define NM1   65535.0f
#define EPSR  0.001f

typedef __attribute__((ext_vector_type(4)))  float          f32x4;
typedef __attribute__((ext_vector_type(16))) float          f32x16;
typedef __attribute__((ext_vector_type(8)))  short          bf16x8;
typedef __attribute__((ext_vector_type(4)))  unsigned short ushort4_t;
typedef __attribute__((ext_vector_type(8)))  unsigned short ushort8_t;

__device__ __forceinline__ unsigned short f2bf(float f){
  unsigned u = __float_as_uint(f);
  u += 0x7fffu + ((u >> 16) & 1u);   // RNE
  return (unsigned short)(u >> 16);
}
__device__ __forceinline__ float bf2f(unsigned short h){
  return __uint_as_float(((unsigned)h) << 16);
}
__device__ __forceinline__ f32x4 mfma16(bf16x8 a, bf16x8 b, f32x4 c){
  return __builtin_amdgcn_mfma_f32_16x16x32_bf16(a, b, c, 0, 0, 0);
}
__device__ __forceinline__ f32x16 mfma32(bf16x8 a, bf16x8 b, f32x16 c){
  return __builtin_amdgcn_mfma_f32_32x32x16_bf16(a, b, c, 0, 0, 0);
}
__device__ __forceinline__ void gld_lds16(const void* g, void* l){
  __builtin_amdgcn_global_load_lds(
      (const __attribute__((address_space(1))) unsigned int*)g,
      (__attribute__((address_space(3))) unsigned int*)l, 16, 0, 0);
}

#define VMCNT(N) asm volatile("s_waitcnt vmcnt(" #N ")" ::: "memory")

// ------- W' in k-chunk-major bf16 layout + STG regularizer accumulation ----
__global__ void k_prep(const float* __restrict__ Wx, const float* __restrict__ Wy,
                       const float* __restrict__ mux, const float* __restrict__ muy,
                       unsigned short* __restrict__ WTx, unsigned short* __restrict__ WTy,
                       float* __restrict__ scal){
  int v = blockIdx.y;
  const float* W  = v ? Wy  : Wx;
  const float* mu = v ? muy : mux;
  unsigned short* WT = v ? WTy : WTx;
  int j = threadIdx.x;
  if (j < 4){
    float ph = 0.5f * (1.f + erff(mu[blockIdx.x * 4 + j] * 1.41421356237f));
    atomicAdd(scal + 2 + v, 9.765625e-5f * ph);
  }
  #pragma unroll
  for (int r = 0; r < 4; ++r){
    int k = blockIdx.x * 4 + r;
    float g = fminf(fmaxf(mu[k] + 0.5f, 0.f), 1.f);
    WT[(size_t)(k >> 3) * 2048 + j * 8 + (k & 7)] = f2bf(g * W[(size_t)k * DD + j]);
  }
}

// ---------------- big GEMM: Xh = X @ W'  -> bf16 ---------------------------
// Best measured config (R13): 512 thr, 8 waves 1x8, tile 64x256, wave 64x32;
// A K=128-chunk 512B bursts -> XOR-swizzled As[2][64][128] (slot^row&15);
// B L2->regs 8 frags/chunk; counted vmcnt {10,8,6,4}. 162us, conflicts ~1M.
__global__ __launch_bounds__(512, 4) void k_gemm11(
    const float* __restrict__ X, const float* __restrict__ Y,
    const unsigned short* __restrict__ WTx, const unsigned short* __restrict__ WTy,
    unsigned short* __restrict__ Xhb, unsigned short* __restrict__ Yhb){
  const float* A = blockIdx.z ? Y : X;
  const unsigned short* WT = blockIdx.z ? WTy : WTx;
  unsigned short* Out = blockIdx.z ? Yhb : Xhb;

  __shared__ unsigned short As[2][64][128];    // 32KB, XOR-swizzled, no pad

  int tid = threadIdx.x, lane = tid & 63, wid = tid >> 6;
  int row0 = blockIdx.x * 64;

  f32x4 acc[4][2] = {};

  int s_row = tid >> 3, s_p = tid & 7;         // 64 rows x 8 slot-pairs
  const float* ap = A + (size_t)(row0 + s_row) * DXF + s_p * 8;

  // B fragment base: col = wid*32 + t*16 + (lane&15); k-group = (lane>>4)
  const unsigned short* bB = WT + (size_t)(lane >> 4) * 2048
                           + (wid * 32 + (lane & 15)) * 8;

  float4 a0, a1, a2, a3;
  auto loadA = [&](int kc){
    const float* p = ap + kc * 128;
    a0 = *(const float4*)(p);
    a1 = *(const float4*)(p + 4);
    a2 = *(const float4*)(p + 64);
    a3 = *(const float4*)(p + 68);
  };
  auto writeA = [&](int b){
    union { unsigned u[4]; ushort8_t v; } w;
    asm("v_cvt_pk_bf16_f32 %0, %1, %2" : "=v"(w.u[0]) : "v"(a0.x), "v"(a0.y));
    asm("v_cvt_pk_bf16_f32 %0, %1, %2" : "=v"(w.u[1]) : "v"(a0.z), "v"(a0.w));
    asm("v_cvt_pk_bf16_f32 %0, %1, %2" : "=v"(w.u[2]) : "v"(a1.x), "v"(a1.y));
    asm("v_cvt_pk_bf16_f32 %0, %1, %2" : "=v"(w.u[3]) : "v"(a1.z), "v"(a1.w));
    *(ushort8_t*)&As[b][s_row][(s_p ^ (s_row & 15)) * 8] = w.v;
    asm("v_cvt_pk_bf16_f32 %0, %1, %2" : "=v"(w.u[0]) : "v"(a2.x), "v"(a2.y));
    asm("v_cvt_pk_bf16_f32 %0, %1, %2" : "=v"(w.u[1]) : "v"(a2.z), "v"(a2.w));
    asm("v_cvt_pk_bf16_f32 %0, %1, %2" : "=v"(w.u[2]) : "v"(a3.x), "v"(a3.y));
    asm("v_cvt_pk_bf16_f32 %0, %1, %2" : "=v"(w.u[3]) : "v"(a3.z), "v"(a3.w));
    *(ushort8_t*)&As[b][s_row][((s_p + 8) ^ (s_row & 15)) * 8] = w.v;
  };

  // prologue: chunk 0 staged synchronously
  loadA(0);
  VMCNT(0);
  writeA(0);
  asm volatile("s_waitcnt lgkmcnt(0)" ::: "memory");
  __builtin_amdgcn_s_barrier();

#define AFRAG(M, S) \
    (*(const bf16x8*)&As[buf][M * 16 + (lane & 15)] \
        [(((S * 4) + (lane >> 4)) ^ (lane & 15)) * 8])
#define GSTEP(S, BA, BB) { \
    bf16x8 af0 = AFRAG(0, S); \
    bf16x8 af1 = AFRAG(1, S); \
    bf16x8 af2 = AFRAG(2, S); \
    bf16x8 af3 = AFRAG(3, S); \
    acc[0][0] = mfma16(af0, BA, acc[0][0]); acc[0][1] = mfma16(af0, BB, acc[0][1]); \
    acc[1][0] = mfma16(af1, BA, acc[1][0]); acc[1][1] = mfma16(af1, BB, acc[1][1]); \
    acc[2][0] = mfma16(af2, BA, acc[2][0]); acc[2][1] = mfma16(af2, BB, acc[2][1]); \
    acc[3][0] = mfma16(af3, BA, acc[3][0]); acc[3][1] = mfma16(af3, BB, acc[3][1]); }

  #pragma unroll
  for (int c = 0; c < 8; ++c){
    int buf = c & 1;
    const unsigned short* bc = bB + c * 32768;
    // issue all 8 B-frags of this chunk (L2 hits), THEN A prefetch
    bf16x8 b0a = *(const bf16x8*)(bc);
    bf16x8 b0b = *(const bf16x8*)(bc + 128);
    bf16x8 b1a = *(const bf16x8*)(bc + 8192);
    bf16x8 b1b = *(const bf16x8*)(bc + 8320);
    bf16x8 b2a = *(const bf16x8*)(bc + 16384);
    bf16x8 b2b = *(const bf16x8*)(bc + 16512);
    bf16x8 b3a = *(const bf16x8*)(bc + 24576);
    bf16x8 b3b = *(const bf16x8*)(bc + 24704);
    asm volatile("" ::: "memory");
    if (c < 7) loadA(c + 1);                   // 4 loads, newest

    if (c < 7) { VMCNT(10); } else { VMCNT(6); }   // B(s0) ready
    __builtin_amdgcn_sched_barrier(0);
    GSTEP(0, b0a, b0b)
    if (c < 7) { VMCNT(8); } else { VMCNT(4); }
    __builtin_amdgcn_sched_barrier(0);
    GSTEP(1, b1a, b1b)
    if (c < 7) { VMCNT(6); } else { VMCNT(2); }
    __builtin_amdgcn_sched_barrier(0);
    GSTEP(2, b2a, b2b)
    if (c < 7) { VMCNT(4); } else { VMCNT(0); }
    __builtin_amdgcn_sched_barrier(0);
    GSTEP(3, b3a, b3b)

    if (c < 7){
      VMCNT(0);                                // A(c+1) regs ready
      __builtin_amdgcn_sched_barrier(0);
      writeA(buf ^ 1);
      asm volatile("s_waitcnt lgkmcnt(0)" ::: "memory");
      __builtin_amdgcn_s_barrier();
    }
  }
#undef GSTEP
#undef AFRAG

  // epilogue: LDS transpose (flat 32KB in As) -> coalesced bf16 stores
  __syncthreads();
  unsigned short* tl = &As[0][0][0];
  #pragma unroll
  for (int r = 0; r < 4; ++r)
    #pragma unroll
    for (int t = 0; t < 2; ++t)
      #pragma unroll
      for (int rr = 0; rr < 4; ++rr){
        int row = r * 16 + (lane >> 4) * 4 + rr;
        int col = wid * 32 + t * 16 + (lane & 15);
        tl[row * 256 + col] = f2bf(acc[r][t][rr]);
      }
  __syncthreads();
  unsigned short* ob = Out + (size_t)row0 * DD;
  #pragma unroll
  for (int r = 0; r < 4; ++r){
    int off = r * 4096 + tid * 8;
    *(ushort8_t*)(ob + off) = *(const ushort8_t*)(tl + off);
  }
}

// ---------------- Gram kernel: split-K partials ----------------------------
__global__ __launch_bounds__(512) void k_gram(
    const unsigned short* __restrict__ Xhb, const unsigned short* __restrict__ Yhb,
    float* __restrict__ part, float* __restrict__ sx, float* __restrict__ sy, int P){
  int type = blockIdx.z;
  int p = blockIdx.x;
  int chunk = N_S / P;
  int r0 = p * chunk;
  const unsigned short* Asrc = (type == 0) ? Xhb : Yhb;
  const unsigned short* Bsrc = (type == 1) ? Yhb : Xhb;
  bool dualB = (type == 2);

  __shared__ unsigned short At[256][40];
  __shared__ unsigned short Bt[256][40];

  int tid = threadIdx.x;
  int lane = tid & 63, wid = tid >> 6;
  int wr = wid >> 1, wc = wid & 1;

  f32x4 acc[4][8] = {};
  float cs0 = 0.f, cs1 = 0.f;

  int cp  = tid & 127;
  int kb0 = tid >> 7;

  unsigned ua[2][4], ub[2][4];

  auto loadT = [&](int ks){
    int base = r0 + ks * 32;
    #pragma unroll
    for (int r = 0; r < 2; ++r){
      int kb = kb0 + r * 4;
      #pragma unroll
      for (int kr = 0; kr < 4; ++kr){
        ua[r][kr] = *(const unsigned*)(Asrc + (size_t)(base + kb * 4 + kr) * DD + cp * 2);
        if (dualB)
          ub[r][kr] = *(const unsigned*)(Bsrc + (size_t)(base + kb * 4 + kr) * DD + cp * 2);
      }
    }
  };
  auto storeT = [&](){
    #pragma unroll
    for (int r = 0; r < 2; ++r){
      int kb = kb0 + r * 4;
      ushort4_t lo = { (unsigned short)ua[r][0], (unsigned short)ua[r][1],
                       (unsigned short)ua[r][2], (unsigned short)ua[r][3] };
      ushort4_t hi = { (unsigned short)(ua[r][0] >> 16), (unsigned short)(ua[r][1] >> 16),
                       (unsigned short)(ua[r][2] >> 16), (unsigned short)(ua[r][3] >> 16) };
      *(ushort4_t*)&At[cp * 2][kb * 4]     = lo;
      *(ushort4_t*)&At[cp * 2 + 1][kb * 4] = hi;
      if (type < 2){
        #pragma unroll
        for (int kr = 0; kr < 4; ++kr){
          cs0 += bf2f((unsigned short)ua[r][kr]);
          cs1 += bf2f((unsigned short)(ua[r][kr] >> 16));
        }
      }
      if (dualB){
        ushort4_t lob = { (unsigned short)ub[r][0], (unsigned short)ub[r][1],
                          (unsigned short)ub[r][2], (unsigned short)ub[r][3] };
        ushort4_t hib = { (unsigned short)(ub[r][0] >> 16), (unsigned short)(ub[r][1] >> 16),
                          (unsigned short)(ub[r][2] >> 16), (unsigned short)(ub[r][3] >> 16) };
        *(ushort4_t*)&Bt[cp * 2][kb * 4]     = lob;
        *(ushort4_t*)&Bt[cp * 2 + 1][kb * 4] = hib;
      }
    }
  };

  unsigned short (*Btp)[40] = dualB ? Bt : At;

  int KS = chunk / 32;
  loadT(0);
  for (int ks = 0; ks < KS; ++ks){
    __syncthreads();
    storeT();
    __syncthreads();
    if (ks + 1 < KS) loadT(ks + 1);
    bf16x8 af[4], bfv[8];
    #pragma unroll
    for (int mi = 0; mi < 4; ++mi)
      af[mi] = *(const bf16x8*)&At[wr * 64 + mi * 16 + (lane & 15)][(lane >> 4) * 8];
    #pragma unroll
    for (int ni = 0; ni < 8; ++ni)
      bfv[ni] = *(const bf16x8*)&Btp[wc * 128 + ni * 16 + (lane & 15)][(lane >> 4) * 8];
    #pragma unroll
    for (int mi = 0; mi < 4; ++mi)
      #pragma unroll
      for (int ni = 0; ni < 8; ++ni)
        acc[mi][ni] = mfma16(af[mi], bfv[ni], acc[mi][ni]);
  }

  float* dst = part + ((size_t)p * 3 + type) * 65536;
  #pragma unroll
  for (int mi = 0; mi < 4; ++mi)
    #pragma unroll
    for (int ni = 0; ni < 8; ++ni)
      #pragma unroll
      for (int rr = 0; rr < 4; ++rr){
        int grow = wr * 64 + mi * 16 + (lane >> 4) * 4 + rr;
        int gcol = wc * 128 + ni * 16 + (lane & 15);
        dst[(size_t)grow * 256 + gcol] = acc[mi][ni][rr];
      }

  if (type < 2){
    __syncthreads();
    float* red = (float*)&At[0][0];
    red[kb0 * 256 + cp * 2]     = cs0;
    red[kb0 * 256 + cp * 2 + 1] = cs1;
    __syncthreads();
    if (tid < 256){
      float s = red[tid] + red[256 + tid] + red[512 + tid] + red[768 + tid];
      atomicAdd((type == 0 ? sx : sy) + tid, s);
    }
  }
}

// -------- reduce partials -> A,B (fp32+bf16), C bf16(+T), inf-norms --------
__global__ void k_reduce(const float* __restrict__ part, const float* __restrict__ sx,
                         const float* __restrict__ sy, float* __restrict__ Am,
                         float* __restrict__ Bm,
                         unsigned short* __restrict__ Abf, unsigned short* __restrict__ Bbf,
                         unsigned short* __restrict__ Cbf, unsigned short* __restrict__ CbfT,
                         float* __restrict__ scal, int P){
  __shared__ float r2[256];
  int i = blockIdx.x, j = threadIdx.x;
  size_t idx = (size_t)i * 256 + j;
  float gxx = 0.f, gyy = 0.f, gyx = 0.f;
  for (int p = 0; p < P; ++p){
    const float* b = part + (size_t)p * 3 * 65536;
    gxx += b[idx];
    gyy += b[65536 + idx];
    gyx += b[131072 + idx];
  }
  float invn1 = 1.f / NM1;
  float invn  = 1.f / (float)N_S;
  float sxi = sx[i], sxj = sx[j], syi = sy[i], syj = sy[j];
  float diag = (i == j) ? 1.f : 0.f;
  float am = (gyy - syi * syj * invn) * invn1 + diag * (2.f * EPSR);
  float bm = (gxx - sxi * sxj * invn) * invn1 + diag * EPSR;
  float cv = (gyx - syi * sxj * invn) * invn1;
  Am[idx] = am;  Bm[idx] = bm;
  Abf[idx] = f2bf(am);
  Bbf[idx] = f2bf(bm);
  Cbf[idx] = f2bf(cv);
  CbfT[(size_t)j * 256 + i] = f2bf(cv);
  r2[j] = fabsf(am);
  __syncthreads();
  for (int s = 128; s > 0; s >>= 1){ if (j < s) r2[j] += r2[j + s]; __syncthreads(); }
  if (j == 0) atomicMax((unsigned*)scal + 5, __float_as_uint(r2[0]));
  __syncthreads();
  r2[j] = fabsf(bm);
  __syncthreads();
  for (int s = 128; s > 0; s >>= 1){ if (j < s) r2[j] += r2[j + s]; __syncthreads(); }
  if (j == 0) atomicMax((unsigned*)scal + 6, __float_as_uint(r2[0]));
}

// -------- X1 = 2aI - a^2 M  (NS step 1 closed form), a = 1.9/||M||inf ------
__global__ void k_x1(const float* __restrict__ Am, const float* __restrict__ Bm,
                     unsigned short* __restrict__ X0, const float* __restrict__ scal){
  int m = blockIdx.y;
  const unsigned* su = (const unsigned*)scal;
  float al = 1.9f / __uint_as_float(su[5 + m]);
  const float* M = m ? Bm : Am;
  int e = blockIdx.x * 512 + threadIdx.x;
  float v = -al * al * M[e];
  if ((e >> 8) == (e & 255)) v += 2.f * al;
  X0[m * 65536 + e] = f2bf(v);
}

// -------- one NS iteration, col-block local: X'_j = 2X_j - X*(M*X_j) -------
__global__ __launch_bounds__(512) void k_it(
    const unsigned short* __restrict__ Abf, const unsigned short* __restrict__ Bbf,
    const unsigned short* __restrict__ Xc, unsigned short* __restrict__ Xn){
  int m = blockIdx.y, j = blockIdx.x;
  const unsigned short* M  = m ? Bbf : Abf;
  const unsigned short* Xm = Xc + m * 65536;
  unsigned short*       Xo = Xn + m * 65536;

  __shared__ unsigned short XJ[32 * 256];
  __shared__ unsigned short TT[32 * 256];

  int tid = threadIdx.x, lane = tid & 63, w = tid >> 6;
  int r31 = lane & 31, kh = lane >> 5;

  #pragma unroll
  for (int i = 0; i < 2; ++i){
    int rl = w * 4 + i * 2 + kh;
    int cg = ((lane & 31) - rl) & 31;
    gld_lds16(Xm + (size_t)(j * 32 + rl) * 256 + cg * 8, &XJ[(w * 4 + i * 2) * 256]);
  }
  asm volatile("s_waitcnt vmcnt(0)" ::: "memory");
  __builtin_amdgcn_s_barrier();

  f32x16 acc = {};
  const unsigned short* arow = M + (size_t)(w * 32 + r31) * 256 + kh * 8;
  #pragma unroll
  for (int ks = 0; ks < 16; ++ks){
    bf16x8 af = *(const bf16x8*)(arow + ks * 16);
    int ch = ((ks * 2 + kh) + r31) & 31;
    bf16x8 bf = *(const bf16x8*)&XJ[r31 * 256 + ch * 8];
    acc = mfma32(af, bf, acc);
  }
  #pragma unroll
  for (int reg = 0; reg < 16; ++reg){
    int kk = w * 32 + (reg & 3) + ((reg >> 2) << 3) + (kh << 2);
    int ch = ((kk >> 3) + r31) & 31;
    TT[r31 * 256 + ch * 8 + (kk & 7)] = f2bf(acc[reg]);
  }
  __syncthreads();

  f32x16 acc2 = {};
  const unsigned short* xrow = Xm + (size_t)(w * 32 + r31) * 256 + kh * 8;
  #pragma unroll
  for (int ks = 0; ks < 16; ++ks){
    bf16x8 af = *(const bf16x8*)(xrow + ks * 16);
    int ch = ((ks * 2 + kh) + r31) & 31;
    bf16x8 bf = *(const bf16x8*)&TT[r31 * 256 + ch * 8];
    acc2 = mfma32(af, bf, acc2);
  }
  #pragma unroll
  for (int reg = 0; reg < 16; ++reg){
    int row = w * 32 + (reg & 3) + ((reg >> 2) << 3) + (kh << 2);
    int ch = ((row >> 3) + r31) & 31;
    float xv = bf2f(XJ[r31 * 256 + ch * 8 + (row & 7)]);
    Xo[(size_t)row * 256 + j * 32 + r31] = f2bf(2.f * xv - acc2[reg]);
  }
}

// -------- U = XA*C (mat0) ; W = C*XB = V^T (mat1) ; f32 outputs ------------
__global__ __launch_bounds__(512) void k_uv(
    const unsigned short* __restrict__ Xf,
    const unsigned short* __restrict__ Cbf, const unsigned short* __restrict__ CbfT,
    float* __restrict__ U, float* __restrict__ W){
  int m = blockIdx.y, j = blockIdx.x;
  __shared__ unsigned short BJ[32 * 256];
  int tid = threadIdx.x, lane = tid & 63, w = tid >> 6;
  int r31 = lane & 31, kh = lane >> 5;
  const unsigned short* Brows = m ? (Xf + 65536) : CbfT;
  const unsigned short* Arows = m ? Cbf : Xf;
  float* D = m ? W : U;

  #pragma unroll
  for (int i = 0; i < 2; ++i){
    int rl = w * 4 + i * 2 + kh;
    int cg = ((lane & 31) - rl) & 31;
    gld_lds16(Brows + (size_t)(j * 32 + rl) * 256 + cg * 8, &BJ[(w * 4 + i * 2) * 256]);
  }
  asm volatile("s_waitcnt vmcnt(0)" ::: "memory");
  __builtin_amdgcn_s_barrier();

  f32x16 acc = {};
  const unsigned short* ar = Arows + (size_t)(w * 32 + r31) * 256 + kh * 8;
  #pragma unroll
  for (int ks = 0; ks < 16; ++ks){
    bf16x8 af = *(const bf16x8*)(ar + ks * 16);
    int ch = ((ks * 2 + kh) + r31) & 31;
    bf16x8 bf = *(const bf16x8*)&BJ[r31 * 256 + ch * 8];
    acc = mfma32(af, bf, acc);
  }
  #pragma unroll
  for (int reg = 0; reg < 16; ++reg){
    int row = w * 32 + (reg & 3) + ((reg >> 2) << 3) + (kh << 2);
    D[(size_t)row * 256 + j * 32 + r31] = acc[reg];
  }
}

// -------- final: loss = -sum(U*W)/256 + regx + regy ------------------------
__global__ __launch_bounds__(1024) void k_fin(const float* __restrict__ U,
                                              const float* __restrict__ W,
                                              const float* __restrict__ scal,
                                              float* __restrict__ out){
  __shared__ float red[1024];
  int tid = threadIdx.x;
  float t = 0.f;
  #pragma unroll
  for (int r = 0; r < 16; ++r){
    int i = r * 4096 + tid * 4;
    float4 u = *(const float4*)(U + i);
    float4 w = *(const float4*)(W + i);
    t += u.x * w.x + u.y * w.y + u.z * w.z + u.w * w.w;
  }
  red[tid] = t; __syncthreads();
  for (int s = 512; s > 0; s >>= 1){ if (tid < s) red[tid] += red[tid + s]; __syncthreads(); }
  if (tid == 0) out[0] = -red[0] / 256.f + scal[2] + scal[3];
}

extern "C" void kernel_launch(void* const* d_in, const int* in_sizes, int n_in,
                              void* d_out, int out_size, void* d_ws, size_t ws_size,
                              hipStream_t stream){
  (void)in_sizes; (void)n_in; (void)out_size;
  const float* X   = (const float*)d_in[0];
  const float* Y   = (const float*)d_in[1];
  const float* mux = (const float*)d_in[2];
  const float* muy = (const float*)d_in[3];
  const float* Wx  = (const float*)d_in[4];
  const float* Wy  = (const float*)d_in[6];
  float* out = (float*)d_out;
  char* ws = (char*)d_ws;

  const size_t MB = 1ull << 20;
  const size_t KB = 1024;
  size_t oXHB = 0;
  size_t oYHB = 32 * MB;
  size_t oWTX = 64 * MB;
  size_t oWTY = oWTX + 512 * KB;
  size_t oSX  = oWTY + 512 * KB;
  size_t oSY  = oSX + 4 * KB;
  size_t oSC  = oSY + 4 * KB;
  size_t oA   = oSC + 4 * KB;
  size_t oB   = oA   + 256 * KB;
  size_t oABF = oB   + 256 * KB;
  size_t oBBF = oABF + 128 * KB;
  size_t oCBF = oBBF + 128 * KB;
  size_t oCBT = oCBF + 128 * KB;
  size_t oX0  = oCBT + 128 * KB;
  size_t oX1  = oX0  + 256 * KB;
  size_t oTB  = oX1  + 256 * KB;
  size_t oU   = oTB  + 256 * KB;
  size_t oV   = oU   + 256 * KB;
  size_t oPart = 68 * MB;

  size_t per = 3ull * 65536 * 4;
  int P = 64;
  while (P > 8 && oPart + (size_t)P * per > ws_size) P >>= 1;

  unsigned short* Xhb = (unsigned short*)(ws + oXHB);
  unsigned short* Yhb = (unsigned short*)(ws + oYHB);
  unsigned short* WTx = (unsigned short*)(ws + oWTX);
  unsigned short* WTy = (unsigned short*)(ws + oWTY);
  float* sx   = (float*)(ws + oSX);
  float* sy   = (float*)(ws + oSY);
  float* scal = (float*)(ws + oSC);
  float* Am   = (float*)(ws + oA);
  float* Bm   = (float*)(ws + oB);
  unsigned short* Abf  = (unsigned short*)(ws + oABF);
  unsigned short* Bbf  = (unsigned short*)(ws + oBBF);
  unsigned short* Cbf  = (unsigned short*)(ws + oCBF);
  unsigned short* CbfT = (unsigned short*)(ws + oCBT);
  unsigned short* X0   = (unsigned short*)(ws + oX0);
  unsigned short* X1   = (unsigned short*)(ws + oX1);
  float* U    = (float*)(ws + oU);
  float* V    = (float*)(ws + oV);
  float* part = (float*)(ws + oPart);

  hipMemsetAsync(ws + oSX, 0, 12 * KB, stream);

  k_prep<<<dim3(256, 2), 256, 0, stream>>>(Wx, Wy, mux, muy, WTx, WTy, scal);
  k_gemm11<<<dim3(1024, 1, 2), 512, 0, stream>>>(X, Y, WTx, WTy, Xhb, Yhb);
  k_gram<<<dim3(P, 1, 3), 512, 0, stream>>>(Xhb, Yhb, part, sx, sy, P);
  k_reduce<<<256, 256, 0, stream>>>(part, sx, sy, Am, Bm, Abf, Bbf, Cbf, CbfT, scal, P);

  k_x1<<<dim3(128, 2), 512, 0, stream>>>(Am, Bm, X0, scal);
  k_it<<<dim3(8, 2), 512, 0, stream>>>(Abf, Bbf, X0, X1);
  k_it<<<dim3(8, 2), 512, 0, stream>>>(Abf, Bbf, X1, X0);
  k_it<<<dim3(8, 2), 512, 0, stream>>>(Abf, Bbf, X0, X1);
  k_it<<<dim3(8, 2), 512, 0, stream>>>(Abf, Bbf, X1, X0);
  k_it<<<dim3(8, 2), 512, 0, stream>>>(Abf, Bbf, X0, X1);   // final in X1
  k_uv<<<dim3(8, 2), 512, 0, stream>>>(X1, Cbf, CbfT, U, V);
  k_fin<<<1, 1024, 0, stream>>>(U, V, scal, out);
}